// Round 4
// baseline (175.929 us; speedup 1.0000x reference)
//
#include <hip/hip_runtime.h>

#define LR 0.01f
#define NSTEPS 100

// Native 4-float vector: __builtin_nontemporal_load/store require a real
// vector type, not HIP's struct-wrapped float4.
typedef float f4 __attribute__((ext_vector_type(4)));

// u_{k+1} = a*u_k + c with a = 1-2*LR*q, c = -LR*p, per element of (B,4),
// q/p = cols 12..15 of the (B,16) Q/p arrays.
//
// R0-R3 lesson: reading 16 B at stride 64 B (one sector per DRAM burst)
// plateaus at ~1.3 TB/s — request-rate limited, not DRAM limited. Fix:
// STREAM Q and p with full contiguous 1 KB coverage per wave-load.
// R4/R5: single-touch streaming -> nontemporal loads/stores (dur 186->174).
// R6: kill the 32 ds_bpermute/thread. Within each contiguous 1 KB block,
// lane L reads tile-local float4 index s_j(L) = 4*(L&15) + ((L>>4)^j^3) —
// a bijection per load j (same 16 sectors, same DRAM behavior), chosen so
// that load j = L>>4 puts lane L's needed float4 (index 4L+3 = cols 12..15
// of row b0+L) directly in its own register. No cross-lane ops remain.
__global__ __launch_bounds__(256) void diffmpc_kernel(
    const f4* __restrict__ Qv,
    const f4* __restrict__ Pv,
    const f4* __restrict__ Uv,
    f4* __restrict__ Ov)
{
    const int wave = (int)((blockIdx.x * blockDim.x + threadIdx.x) >> 6);
    const int lane = (int)(threadIdx.x & 63);
    const int lo   = lane & 15;
    const int hi   = lane >> 4;
    const long b0   = (long)wave << 6;   // first row of this wave's 64-row tile
    const long base = b0 * 4;            // tile start, in float4 units

    // Permuted full-coverage streaming: load j covers float4s [64j, 64j+64)
    // of the tile (contiguous 1 KB), lane L at offset 4*lo + (hi^j^3).
    f4 q[4], pr[4];
#pragma unroll
    for (int j = 0; j < 4; ++j) {
        const int s = 4 * lo + (hi ^ j ^ 3);
        q[j]  = __builtin_nontemporal_load(&Qv[base + 64 * j + s]);
        pr[j] = __builtin_nontemporal_load(&Pv[base + 64 * j + s]);
    }
    f4 u = __builtin_nontemporal_load(&Uv[b0 + lane]);  // (B,4) rows: natively coalesced

    // Lane L's needed data sits in register block j = hi.
    f4 q4 = q[0], p4 = pr[0];
#pragma unroll
    for (int j = 1; j < 4; ++j) {
        if (hi == j) { q4 = q[j]; p4 = pr[j]; }
    }

    const float ax = fmaf(-2.0f * LR, q4.x, 1.0f);
    const float ay = fmaf(-2.0f * LR, q4.y, 1.0f);
    const float az = fmaf(-2.0f * LR, q4.z, 1.0f);
    const float aw = fmaf(-2.0f * LR, q4.w, 1.0f);
    const float cx = -LR * p4.x;
    const float cy = -LR * p4.y;
    const float cz = -LR * p4.z;
    const float cw = -LR * p4.w;

#pragma unroll 10
    for (int i = 0; i < NSTEPS; ++i) {
        u.x = fmaf(ax, u.x, cx);
        u.y = fmaf(ay, u.y, cy);
        u.z = fmaf(az, u.z, cz);
        u.w = fmaf(aw, u.w, cw);
    }

    __builtin_nontemporal_store(u, &Ov[b0 + lane]);
}

extern "C" void kernel_launch(void* const* d_in, const int* in_sizes, int n_in,
                              void* d_out, int out_size, void* d_ws, size_t ws_size,
                              hipStream_t stream) {
    // Inputs: x_init (B,12) [UNUSED], Q (B,16), p (B,16), u_init (B,4)
    const f4* Qv = (const f4*)d_in[1];
    const f4* Pv = (const f4*)d_in[2];
    const f4* Uv = (const f4*)d_in[3];
    f4* Ov = (f4*)d_out;

    const int B = in_sizes[3] / 4;   // 1,048,576 rows
    const int waves = B / 64;        // 16,384 waves (exact)
    const int block = 256;           // 4 waves/block
    const int grid = waves / 4;      // 4,096 blocks

    diffmpc_kernel<<<grid, block, 0, stream>>>(Qv, Pv, Uv, Ov);
}